// Round 7
// baseline (248.882 us; speedup 1.0000x reference)
//
#include <hip/hip_runtime.h>
#include <hip/hip_bf16.h>
#include <math.h>

#define B_  4
#define S_  2048
#define D_  256
#define H_  8
#define HD_ 32
// 1/sqrt(32) * log2(e): folded into Q so softmax is a bare exp2
#define QSCALE 0.25504175929589786f

typedef short  bf16x8 __attribute__((ext_vector_type(8)));
typedef float  f32x4  __attribute__((ext_vector_type(4)));
typedef unsigned short ushort_t;
typedef unsigned int   uint_t;

__device__ __forceinline__ ushort_t f2b(float f) {
    union { float f; unsigned u; } v; v.f = f;
    unsigned r = (v.u + 0x7FFFu + ((v.u >> 16) & 1u)) >> 16;
    return (ushort_t)r;
}
__device__ __forceinline__ float b2f(ushort_t s) {
    return __uint_as_float((uint_t)s << 16);
}

// ---------------- reductions ----------------
__device__ __forceinline__ float wave_sum(float v) {
#pragma unroll
    for (int o = 32; o > 0; o >>= 1) v += __shfl_down(v, o, 64);
    return v;
}
__device__ __forceinline__ float block_sum256(float v, float* scr) {
    v = wave_sum(v);
    int lane = threadIdx.x & 63, wid = threadIdx.x >> 6;
    if (lane == 0) scr[wid] = v;
    __syncthreads();
    float r = scr[0] + scr[1] + scr[2] + scr[3];
    __syncthreads();
    return r;
}

// ---------------- merged prep: adj->bits | weight cvt+frag-reorder | layernorm ----------------
#define WQ_SZ 196608   // 768*256
#define WS_SZ 65536    // 256*256
#define NB_ADJ 65536   // (4*2048*2048)/256
#define NB_WC  2560    // (WQ_SZ+7*WS_SZ)/256
#define NB_LN  8192
__global__ __launch_bounds__(256)
void prep_kernel(const int* __restrict__ adj, uint_t* __restrict__ bits,
                 const float* __restrict__ w0, const float* __restrict__ w1,
                 const float* __restrict__ w2, const float* __restrict__ w3,
                 const float* __restrict__ w4, const float* __restrict__ w5,
                 const float* __restrict__ w6, const float* __restrict__ w7,
                 ushort_t* __restrict__ wout,
                 const float* __restrict__ x, const float* __restrict__ g,
                 const float* __restrict__ bb, ushort_t* __restrict__ xn_b) {
    __shared__ float scr[4];
    int blk = blockIdx.x, tid = threadIdx.x;
    if (blk < NB_ADJ) {
        size_t i = (size_t)blk * 256 + tid;
        unsigned long long m = __ballot(adj[i] != 0);
        int lane = tid & 63;
        size_t wbase = ((size_t)blk * 256 + (tid & ~63)) >> 5;
        if (lane == 0)  bits[wbase]     = (uint_t)m;
        if (lane == 32) bits[wbase + 1] = (uint_t)(m >> 32);
    } else if (blk < NB_ADJ + NB_WC) {
        int idx = (blk - NB_ADJ) * 256 + tid;
        const float* src; int o;
        if (idx < WQ_SZ) { src = w0; o = idx; }
        else {
            int j = idx - WQ_SZ, seg = j >> 16; o = j & (WS_SZ - 1);
            src = (seg == 0) ? w1 : (seg == 1) ? w2 : (seg == 2) ? w3 :
                  (seg == 3) ? w4 : (seg == 4) ? w5 : (seg == 5) ? w6 : w7;
        }
        int j  = o & 7;
        int l  = (o >> 3) & 15;
        int qd = (o >> 7) & 3;
        int ks = (o >> 9) & 7;
        int ct = o >> 12;
        wout[idx] = f2b(src[(ct * 16 + l) * 256 + ks * 32 + qd * 8 + j]);
    } else {
        size_t base = (size_t)(blk - NB_ADJ - NB_WC) * D_;
        float v  = x[base + tid];
        float mu = block_sum256(v, scr) * (1.0f / D_);
        float d  = v - mu;
        float var = block_sum256(d * d, scr) * (1.0f / D_);
        float rstd = rsqrtf(var + 1e-5f);
        xn_b[base + tid] = f2b(d * rstd * g[tid] + bb[tid]);
    }
}

// ---------------- QKV GEMM + transposed V emission ----------------
// grid (12, 128). Emits qkv_b (row-major, Q pre-scaled by QSCALE) and
// vT[(b*8+h)*32 + d][s] (key-major V) for conflict-free attn staging.
__global__ __launch_bounds__(256)
void gemm_qkv(const ushort_t* __restrict__ A, const ushort_t* __restrict__ Wf,
              const float* __restrict__ bias, ushort_t* __restrict__ outb,
              ushort_t* __restrict__ vT) {
    __shared__ ushort_t Sa[64][264];
    int tid = threadIdx.x;
    int wave = tid >> 6, lane = tid & 63, l = lane & 15, quad = lane >> 4;
    int wm = wave >> 1, wn = wave & 1;
    int m0 = blockIdx.y * 64, n0 = blockIdx.x * 64;
    {
        int row = tid >> 2, c0 = (tid & 3) * 64;
        const ushort_t* ap = A + (size_t)(m0 + row) * 256 + c0;
#pragma unroll
        for (int j = 0; j < 8; ++j)
            *(uint4*)&Sa[row][c0 + 8 * j] = ((const uint4*)ap)[j];
    }
    __syncthreads();

    bf16x8 af[2][8];
#pragma unroll
    for (int mt = 0; mt < 2; ++mt)
#pragma unroll
        for (int ks = 0; ks < 8; ++ks)
            af[mt][ks] = *(const bf16x8*)&Sa[wm * 32 + mt * 16 + l][ks * 32 + quad * 8];

    f32x4 acc[2][2];
#pragma unroll
    for (int i = 0; i < 2; ++i)
#pragma unroll
        for (int j = 0; j < 2; ++j) acc[i][j] = (f32x4){0.f, 0.f, 0.f, 0.f};

#pragma unroll
    for (int nt = 0; nt < 2; ++nt) {
        int ct = (n0 >> 4) + wn * 2 + nt;
        bf16x8 wfr[8];
#pragma unroll
        for (int ks = 0; ks < 8; ++ks)
            wfr[ks] = *(const bf16x8*)(Wf + (((size_t)ct * 8 + ks) * 64 + lane) * 8);
#pragma unroll
        for (int ks = 0; ks < 8; ++ks) {
            acc[0][nt] = __builtin_amdgcn_mfma_f32_16x16x32_bf16(af[0][ks], wfr[ks], acc[0][nt], 0, 0, 0);
            acc[1][nt] = __builtin_amdgcn_mfma_f32_16x16x32_bf16(af[1][ks], wfr[ks], acc[1][nt], 0, 0, 0);
        }
    }

    // epilogue: stage 64x64 bf16 tile in LDS (pitch 72), coalesced stores
    __syncthreads();
    ushort_t* So = &Sa[0][0];
#pragma unroll
    for (int nt = 0; nt < 2; ++nt) {
        int col = wn * 32 + nt * 16 + l;
        int gcol = n0 + col;
        float bv = bias[gcol];
        float qs = ((gcol % 96) < 32) ? QSCALE : 1.0f;
#pragma unroll
        for (int mt = 0; mt < 2; ++mt)
#pragma unroll
            for (int r = 0; r < 4; ++r) {
                int row = wm * 32 + mt * 16 + quad * 4 + r;
                So[row * 72 + col] = f2b((acc[mt][nt][r] + bv) * qs);
            }
    }
    __syncthreads();
    {
        int row = tid >> 2, seg = tid & 3;
        uint4 v0 = *(uint4*)&So[row * 72 + seg * 16];
        uint4 v1 = *(uint4*)&So[row * 72 + seg * 16 + 8];
        ushort_t* op = outb + (size_t)(m0 + row) * 768 + n0 + seg * 16;
        ((uint4*)op)[0] = v0;
        ((uint4*)op)[1] = v1;
    }

    // transposed V emission (tiles with n0%96 in {64,32} contain a 32-col V stripe)
    int vs = n0 % 96;
    if (vs != 0) {
        int vloc = (vs == 64) ? 0 : 32;            // local col of V stripe
        int h  = (n0 + vloc) / 96;
        int b  = m0 >> 11;
        int s0 = m0 & (S_ - 1);
        ushort_t* vstage = &Sa[0][0] + 8192;       // 32 rows x pitch 72 (past So's 4608)
        // phase A: column-read So (free: 16 banks x broadcast pairs), pack, stage
        {
            int c = tid & 31, seg = tid >> 5;      // 8 segs x 8 tokens
            ushort_t tmp[8];
#pragma unroll
            for (int i = 0; i < 8; ++i)
                tmp[i] = So[(seg * 8 + i) * 72 + vloc + c];
            uint_t u[4];
#pragma unroll
            for (int i = 0; i < 4; ++i)
                u[i] = (uint_t)tmp[2 * i] | ((uint_t)tmp[2 * i + 1] << 16);
            *(uint4*)&vstage[c * 72 + seg * 8] = make_uint4(u[0], u[1], u[2], u[3]);
        }
        __syncthreads();
        // phase B: row-read vstage (group-balanced), coalesced global store
        {
            int d = tid >> 3, tseg = tid & 7;
            uint4 v = *(uint4*)&vstage[d * 72 + tseg * 8];
            *(uint4*)&vT[((size_t)(b * 8 + h) * 32 + d) * S_ + s0 + tseg * 8] = v;
        }
    }
}

// ---------------- fully fused post-attention (frag-ordered weights) ----------------
__global__ __launch_bounds__(256)
void fused_gate(const ushort_t* __restrict__ attn_b, const float* __restrict__ xf,
                const ushort_t* __restrict__ wfc, const ushort_t* __restrict__ wz,
                const ushort_t* __restrict__ uz, const ushort_t* __restrict__ wr,
                const ushort_t* __restrict__ ur, const ushort_t* __restrict__ wg,
                const ushort_t* __restrict__ ug, const float* __restrict__ bfc,
                const float* __restrict__ bz, float* __restrict__ out) {
    __shared__ ushort_t Sa[16][264];
    __shared__ ushort_t Sx[16][264];
    __shared__ ushort_t Sy[16][264];
    __shared__ ushort_t St[16][264];
    int tid = threadIdx.x;
    int wave = tid >> 6, lane = tid & 63, l = lane & 15, quad = lane >> 4;
    int m0 = blockIdx.x * 16;
    int colbase = wave * 64;

    {
        int row = tid >> 4, c0 = (tid & 15) * 16;
        const ushort_t* ap = attn_b + (size_t)(m0 + row) * 256 + c0;
        uint4 a0 = ((const uint4*)ap)[0];
        uint4 a1 = ((const uint4*)ap)[1];
        *(uint4*)&Sa[row][c0] = a0;
        *(uint4*)&Sa[row][c0 + 8] = a1;
        const float4* xp = (const float4*)(xf + (size_t)(m0 + row) * 256 + c0);
        float4 f0 = xp[0], f1 = xp[1], f2_ = xp[2], f3 = xp[3];
        union { __hip_bfloat162 h[4]; uint4 u; } p0, p1;
        p0.h[0] = __float22bfloat162_rn(make_float2(f0.x, f0.y));
        p0.h[1] = __float22bfloat162_rn(make_float2(f0.z, f0.w));
        p0.h[2] = __float22bfloat162_rn(make_float2(f1.x, f1.y));
        p0.h[3] = __float22bfloat162_rn(make_float2(f1.z, f1.w));
        p1.h[0] = __float22bfloat162_rn(make_float2(f2_.x, f2_.y));
        p1.h[1] = __float22bfloat162_rn(make_float2(f2_.z, f2_.w));
        p1.h[2] = __float22bfloat162_rn(make_float2(f3.x, f3.y));
        p1.h[3] = __float22bfloat162_rn(make_float2(f3.z, f3.w));
        *(uint4*)&Sx[row][c0]     = p0.u;
        *(uint4*)&Sx[row][c0 + 8] = p1.u;
    }
    __syncthreads();

    {
        bf16x8 af[8];
#pragma unroll
        for (int ks = 0; ks < 8; ++ks)
            af[ks] = *(const bf16x8*)&Sa[l][ks * 32 + quad * 8];
        f32x4 ya[4];
#pragma unroll
        for (int nt = 0; nt < 4; ++nt) ya[nt] = (f32x4){0.f, 0.f, 0.f, 0.f};
#pragma unroll
        for (int nt = 0; nt < 4; ++nt) {
            size_t fb = ((size_t)(wave * 4 + nt) * 8) * 512 + lane * 8;
#pragma unroll
            for (int ks = 0; ks < 8; ++ks) {
                bf16x8 wfr = *(const bf16x8*)(wfc + fb + ks * 512);
                ya[nt] = __builtin_amdgcn_mfma_f32_16x16x32_bf16(af[ks], wfr, ya[nt], 0, 0, 0);
            }
        }
#pragma unroll
        for (int nt = 0; nt < 4; ++nt) {
            int col = colbase + nt * 16 + l;
            float bv = bfc[col];
#pragma unroll
            for (int r = 0; r < 4; ++r)
                Sy[quad * 4 + r][col] = f2b(fmaxf(ya[nt][r] + bv, 0.0f));
        }
    }
    __syncthreads();

    f32x4 az[4], ar[4], ag[4];
#pragma unroll
    for (int nt = 0; nt < 4; ++nt) {
        az[nt] = (f32x4){0.f, 0.f, 0.f, 0.f};
        ar[nt] = (f32x4){0.f, 0.f, 0.f, 0.f};
        ag[nt] = (f32x4){0.f, 0.f, 0.f, 0.f};
    }
#pragma unroll
    for (int nt = 0; nt < 4; ++nt) {
        size_t fb = ((size_t)(wave * 4 + nt) * 8) * 512 + lane * 8;
#pragma unroll
        for (int ks = 0; ks < 8; ++ks) {
            bf16x8 fy = *(const bf16x8*)&Sy[l][ks * 32 + quad * 8];
            bf16x8 fx = *(const bf16x8*)&Sx[l][ks * 32 + quad * 8];
            bf16x8 fz  = *(const bf16x8*)(wz + fb + ks * 512);
            bf16x8 fuz = *(const bf16x8*)(uz + fb + ks * 512);
            bf16x8 fr  = *(const bf16x8*)(wr + fb + ks * 512);
            bf16x8 fur = *(const bf16x8*)(ur + fb + ks * 512);
            bf16x8 fg  = *(const bf16x8*)(wg + fb + ks * 512);
            az[nt] = __builtin_amdgcn_mfma_f32_16x16x32_bf16(fy, fz,  az[nt], 0, 0, 0);
            az[nt] = __builtin_amdgcn_mfma_f32_16x16x32_bf16(fx, fuz, az[nt], 0, 0, 0);
            ar[nt] = __builtin_amdgcn_mfma_f32_16x16x32_bf16(fy, fr,  ar[nt], 0, 0, 0);
            ar[nt] = __builtin_amdgcn_mfma_f32_16x16x32_bf16(fx, fur, ar[nt], 0, 0, 0);
            ag[nt] = __builtin_amdgcn_mfma_f32_16x16x32_bf16(fy, fg,  ag[nt], 0, 0, 0);
        }
    }
#pragma unroll
    for (int nt = 0; nt < 4; ++nt) {
        int col = colbase + nt * 16 + l;
        float bzv = bz[col];
#pragma unroll
        for (int r = 0; r < 4; ++r) {
            int row = quad * 4 + r;
            az[nt][r] = 1.0f / (1.0f + __expf(-(az[nt][r] + bzv)));
            float rr  = 1.0f / (1.0f + __expf(-ar[nt][r]));
            St[row][col] = f2b(rr * b2f(Sx[row][col]));
        }
    }
    __syncthreads();

    f32x4 fcc[4];
#pragma unroll
    for (int nt = 0; nt < 4; ++nt) fcc[nt] = (f32x4){0.f, 0.f, 0.f, 0.f};
#pragma unroll
    for (int nt = 0; nt < 4; ++nt) {
        size_t fb = ((size_t)(wave * 4 + nt) * 8) * 512 + lane * 8;
#pragma unroll
        for (int ks = 0; ks < 8; ++ks) {
            bf16x8 ft = *(const bf16x8*)&St[l][ks * 32 + quad * 8];
            bf16x8 fu = *(const bf16x8*)(ug + fb + ks * 512);
            fcc[nt] = __builtin_amdgcn_mfma_f32_16x16x32_bf16(ft, fu, fcc[nt], 0, 0, 0);
        }
    }
#pragma unroll
    for (int nt = 0; nt < 4; ++nt) {
        int col = colbase + nt * 16 + l;
#pragma unroll
        for (int r = 0; r < 4; ++r) {
            int row = quad * 4 + r;
            float v = ag[nt][r] + fcc[nt][r];
            float e = __expf(2.0f * v);
            float h = 1.0f - 2.0f / (e + 1.0f);
            float zz = az[nt][r];
            size_t idx = (size_t)(m0 + row) * 256 + col;
            out[idx] = (1.0f - zz) * xf[idx] + zz * h;
        }
    }
}

// ---------------- MFMA flash attention: dbuf single-barrier, vT staging, exp2 ----------------
// grid (S/64, B*H), block 256. Q pre-scaled by 1/sqrt(32)*log2e in QKV epilogue.
__global__ __launch_bounds__(256)
void attn_kernel(const ushort_t* __restrict__ qkvb, const ushort_t* __restrict__ vT,
                 const uint_t* __restrict__ abits, ushort_t* __restrict__ attn_b) {
    __shared__ ushort_t Ks[2][64][40];
    __shared__ ushort_t Vt[2][32][72];
    __shared__ ushort_t Ps[64][72];

    int tid = threadIdx.x;
    int wave = tid >> 6, lane = tid & 63, l = lane & 15, quad = lane >> 4;
    int q0 = blockIdx.x * 64;
    int n  = blockIdx.y;
    int b = n >> 3, h = n & 7;
    int bp = n & 3, hp = n >> 2;

    const ushort_t* base = qkvb + (size_t)b * S_ * 768 + h * 96;
    int myq = wave * 16 + l;

    bf16x8 qf = *(const bf16x8*)(base + (size_t)(q0 + myq) * 768 + quad * 8);

    f32x4 oacc[2];
    oacc[0] = (f32x4){0.f, 0.f, 0.f, 0.f};
    oacc[1] = (f32x4){0.f, 0.f, 0.f, 0.f};
    float lsum = 0.0f;

    // staging maps (all group-balanced at these pitches)
    int skey = tid >> 2, spart = tid & 3;
    int kcol = (spart * 8) ^ (((skey >> 3) & 1) << 3);
    int vd = tid >> 3, vk = (tid & 7) * 8;
    const ushort_t* vptr = vT + ((size_t)n * 32 + vd) * S_ + vk;
    const uint_t* aptr = abits + ((size_t)b * S_ + q0 + myq) * 64;

    uint4 kv = *(const uint4*)(base + (size_t)skey * 768 + 32 + spart * 8);
    uint4 vv = *(const uint4*)(vptr);
    uint2 aw = *(const uint2*)(aptr);

    for (int k0 = 0; k0 < S_; k0 += 64) {
        int cur = (k0 >> 6) & 1;
        *(uint4*)&Ks[cur][skey][kcol] = kv;
        *(uint4*)&Vt[cur][vd][vk] = vv;
        uint_t aw0 = aw.x, aw1 = aw.y;
        if (k0 + 64 < S_) {
            kv = *(const uint4*)(base + (size_t)(k0 + 64 + skey) * 768 + 32 + spart * 8);
            vv = *(const uint4*)(vptr + k0 + 64);
            aw = *(const uint2*)(aptr + ((k0 + 64) >> 5));
        }
        __syncthreads();

#pragma unroll
        for (int t4 = 0; t4 < 4; ++t4) {
            bf16x8 kf = *(const bf16x8*)&Ks[cur][t4 * 16 + l][(quad * 8) ^ ((l >> 3) << 3)];
            f32x4 z = (f32x4){0.f, 0.f, 0.f, 0.f};
            f32x4 sc = __builtin_amdgcn_mfma_f32_16x16x32_bf16(kf, qf, z, 0, 0, 0);
            uint_t w = (t4 & 2) ? aw1 : aw0;
            uint_t wq = w >> ((t4 & 1) * 16 + quad * 4);
            float p[4];
#pragma unroll
            for (int r = 0; r < 4; ++r) {
                uint_t mneg = 0u - ((wq >> r) & 1u);
                float e = exp2f(sc[r]);
                p[r] = __uint_as_float(__float_as_uint(e) & mneg);
                lsum += p[r];
            }
            union { __hip_bfloat162 b2[2]; uint2 u2; } pk;
            pk.b2[0] = __float22bfloat162_rn(make_float2(p[0], p[1]));
            pk.b2[1] = __float22bfloat162_rn(make_float2(p[2], p[3]));
            *(uint2*)&Ps[myq][t4 * 16 + quad * 4] = pk.u2;
        }

#pragma unroll
        for (int ks = 0; ks < 2; ++ks) {
            bf16x8 pf = *(const bf16x8*)&Ps[wave * 16 + l][ks * 32 + quad * 8];
#pragma unroll
            for (int mt = 0; mt < 2; ++mt) {
                bf16x8 vf = *(const bf16x8*)&Vt[cur][mt * 16 + l][ks * 32 + quad * 8];
                oacc[mt] = __builtin_amdgcn_mfma_f32_16x16x32_bf16(vf, pf, oacc[mt], 0, 0, 0);
            }
        }
    }

    lsum += __shfl_xor(lsum, 16, 64);
    lsum += __shfl_xor(lsum, 32, 64);
    float linv = 1.0f / lsum;

    // coalesced epilogue: stage 64x32 tile in LDS (reuse Ks), uint4 stores
    __syncthreads();
    ushort_t* Ost = &Ks[0][0][0];   // stride 40
#pragma unroll
    for (int mt = 0; mt < 2; ++mt)
#pragma unroll
        for (int r = 0; r < 4; ++r)
            Ost[myq * 40 + mt * 16 + quad * 4 + r] = f2b(oacc[mt][r] * linv);
    __syncthreads();
    {
        int q = tid >> 2, part = tid & 3;
        uint4 v = *(uint4*)&Ost[q * 40 + part * 8];
        *(uint4*)&attn_b[((size_t)(bp * S_ + q0 + q)) * 256 + hp * 32 + part * 8] = v;
    }
}

// ---------------- launch ----------------
extern "C" void kernel_launch(void* const* d_in, const int* in_sizes, int n_in,
                              void* d_out, int out_size, void* d_ws, size_t ws_size,
                              hipStream_t stream) {
    const float* x     = (const float*)d_in[0];
    const int*   adj   = (const int*)d_in[1];
    const float* w_qkv = (const float*)d_in[2];
    const float* b_qkv = (const float*)d_in[3];
    const float* ln_g  = (const float*)d_in[4];
    const float* ln_b  = (const float*)d_in[5];
    const float* w_fc  = (const float*)d_in[6];
    const float* b_fc  = (const float*)d_in[7];
    const float* w_z   = (const float*)d_in[8];
    const float* b_z   = (const float*)d_in[9];
    const float* u_z   = (const float*)d_in[10];
    const float* w_r   = (const float*)d_in[11];
    const float* u_r   = (const float*)d_in[12];
    const float* w_g   = (const float*)d_in[13];
    const float* u_g   = (const float*)d_in[14];
    float* out = (float*)d_out;

    const size_t TOK  = (size_t)B_ * S_;       // 8192
    const size_t TOKD = TOK * D_;              // 2,097,152
    ushort_t* xn_b   = (ushort_t*)d_ws;
    ushort_t* qkv_b  = xn_b + TOKD;            // TOK*768
    ushort_t* attn_b = qkv_b + TOK * 768;
    ushort_t* wb     = attn_b + TOKD;          // 655,360 elems (frag-ordered)
    uint_t*   bits   = (uint_t*)(wb + WQ_SZ + 7 * WS_SZ);   // 524,288 words
    ushort_t* vTb    = (ushort_t*)(bits + (size_t)B_ * S_ * S_ / 32);  // 1024*2048

    ushort_t* wq_b  = wb;
    ushort_t* wfc_b = wb + WQ_SZ;
    ushort_t* wz_b  = wfc_b + WS_SZ;
    ushort_t* uz_b  = wz_b + WS_SZ;
    ushort_t* wr_b  = uz_b + WS_SZ;
    ushort_t* ur_b  = wr_b + WS_SZ;
    ushort_t* wg_b  = ur_b + WS_SZ;
    ushort_t* ug_b  = wg_b + WS_SZ;

    prep_kernel<<<NB_ADJ + NB_WC + NB_LN, 256, 0, stream>>>(
        adj, bits, w_qkv, w_fc, w_z, u_z, w_r, u_r, w_g, u_g, wb,
        x, ln_g, ln_b, xn_b);

    gemm_qkv<<<dim3(12, 128), 256, 0, stream>>>(xn_b, wq_b, b_qkv, qkv_b, vTb);

    attn_kernel<<<dim3(S_ / 64, B_ * H_), 256, 0, stream>>>(qkv_b, vTb, bits, attn_b);

    fused_gate<<<512, 256, 0, stream>>>(
        attn_b, x, wfc_b, wz_b, uz_b, wr_b, ur_b, wg_b, ug_b, b_fc, b_z, out);
}

// Round 8
// 239.864 us; speedup vs baseline: 1.0376x; 1.0376x over previous
//
#include <hip/hip_runtime.h>
#include <hip/hip_bf16.h>
#include <math.h>

#define B_  4
#define S_  2048
#define D_  256
#define H_  8
#define HD_ 32
// 1/sqrt(32) * log2(e): folded into Q so softmax is a bare exp2
#define QSCALE 0.25504175929589786f

typedef short  bf16x8 __attribute__((ext_vector_type(8)));
typedef float  f32x4  __attribute__((ext_vector_type(4)));
typedef unsigned short ushort_t;
typedef unsigned int   uint_t;

__device__ __forceinline__ ushort_t f2b(float f) {
    union { float f; unsigned u; } v; v.f = f;
    unsigned r = (v.u + 0x7FFFu + ((v.u >> 16) & 1u)) >> 16;
    return (ushort_t)r;
}
__device__ __forceinline__ float b2f(ushort_t s) {
    return __uint_as_float((uint_t)s << 16);
}

// ---------------- reductions ----------------
__device__ __forceinline__ float wave_sum(float v) {
#pragma unroll
    for (int o = 32; o > 0; o >>= 1) v += __shfl_down(v, o, 64);
    return v;
}
__device__ __forceinline__ float block_sum256(float v, float* scr) {
    v = wave_sum(v);
    int lane = threadIdx.x & 63, wid = threadIdx.x >> 6;
    if (lane == 0) scr[wid] = v;
    __syncthreads();
    float r = scr[0] + scr[1] + scr[2] + scr[3];
    __syncthreads();
    return r;
}

// ---------------- merged prep: adj->bits | weight cvt+frag-reorder | layernorm ----------------
#define WQ_SZ 196608   // 768*256
#define WS_SZ 65536    // 256*256
#define NB_ADJ 8192    // (4*2048*2048)/256/8  (8 groups per block)
#define NB_WC  2560    // (WQ_SZ+7*WS_SZ)/256
#define NB_LN  8192
__global__ __launch_bounds__(256)
void prep_kernel(const int* __restrict__ adj, uint_t* __restrict__ bits,
                 const float* __restrict__ w0, const float* __restrict__ w1,
                 const float* __restrict__ w2, const float* __restrict__ w3,
                 const float* __restrict__ w4, const float* __restrict__ w5,
                 const float* __restrict__ w6, const float* __restrict__ w7,
                 ushort_t* __restrict__ wout,
                 const float* __restrict__ x, const float* __restrict__ g,
                 const float* __restrict__ bb, ushort_t* __restrict__ xn_b) {
    __shared__ float scr[4];
    int blk = blockIdx.x, tid = threadIdx.x;
    if (blk < NB_ADJ) {
        int lane = tid & 63;
#pragma unroll
        for (int gp = 0; gp < 8; ++gp) {
            size_t i = ((size_t)blk * 8 + gp) * 256 + tid;
            unsigned long long m = __ballot(adj[i] != 0);
            size_t wbase = (((size_t)blk * 8 + gp) * 256 + (tid & ~63)) >> 5;
            if (lane == 0)  bits[wbase]     = (uint_t)m;
            if (lane == 32) bits[wbase + 1] = (uint_t)(m >> 32);
        }
    } else if (blk < NB_ADJ + NB_WC) {
        int idx = (blk - NB_ADJ) * 256 + tid;
        const float* src; int o;
        if (idx < WQ_SZ) { src = w0; o = idx; }
        else {
            int j = idx - WQ_SZ, seg = j >> 16; o = j & (WS_SZ - 1);
            src = (seg == 0) ? w1 : (seg == 1) ? w2 : (seg == 2) ? w3 :
                  (seg == 3) ? w4 : (seg == 4) ? w5 : (seg == 5) ? w6 : w7;
        }
        int j  = o & 7;
        int l  = (o >> 3) & 15;
        int qd = (o >> 7) & 3;
        int ks = (o >> 9) & 7;
        int ct = o >> 12;
        wout[idx] = f2b(src[(ct * 16 + l) * 256 + ks * 32 + qd * 8 + j]);
    } else {
        size_t base = (size_t)(blk - NB_ADJ - NB_WC) * D_;
        float v  = x[base + tid];
        float mu = block_sum256(v, scr) * (1.0f / D_);
        float d  = v - mu;
        float var = block_sum256(d * d, scr) * (1.0f / D_);
        float rstd = rsqrtf(var + 1e-5f);
        xn_b[base + tid] = f2b(d * rstd * g[tid] + bb[tid]);
    }
}

// ---------------- QKV GEMM + transposed V emission ----------------
__global__ __launch_bounds__(256)
void gemm_qkv(const ushort_t* __restrict__ A, const ushort_t* __restrict__ Wf,
              const float* __restrict__ bias, ushort_t* __restrict__ outb,
              ushort_t* __restrict__ vT) {
    __shared__ ushort_t Sa[64][264];
    int tid = threadIdx.x;
    int wave = tid >> 6, lane = tid & 63, l = lane & 15, quad = lane >> 4;
    int wm = wave >> 1, wn = wave & 1;
    int m0 = blockIdx.y * 64, n0 = blockIdx.x * 64;
    {
        int row = tid >> 2, c0 = (tid & 3) * 64;
        const ushort_t* ap = A + (size_t)(m0 + row) * 256 + c0;
#pragma unroll
        for (int j = 0; j < 8; ++j)
            *(uint4*)&Sa[row][c0 + 8 * j] = ((const uint4*)ap)[j];
    }
    __syncthreads();

    bf16x8 af[2][8];
#pragma unroll
    for (int mt = 0; mt < 2; ++mt)
#pragma unroll
        for (int ks = 0; ks < 8; ++ks)
            af[mt][ks] = *(const bf16x8*)&Sa[wm * 32 + mt * 16 + l][ks * 32 + quad * 8];

    f32x4 acc[2][2];
#pragma unroll
    for (int i = 0; i < 2; ++i)
#pragma unroll
        for (int j = 0; j < 2; ++j) acc[i][j] = (f32x4){0.f, 0.f, 0.f, 0.f};

#pragma unroll
    for (int nt = 0; nt < 2; ++nt) {
        int ct = (n0 >> 4) + wn * 2 + nt;
        bf16x8 wfr[8];
#pragma unroll
        for (int ks = 0; ks < 8; ++ks)
            wfr[ks] = *(const bf16x8*)(Wf + (((size_t)ct * 8 + ks) * 64 + lane) * 8);
#pragma unroll
        for (int ks = 0; ks < 8; ++ks) {
            acc[0][nt] = __builtin_amdgcn_mfma_f32_16x16x32_bf16(af[0][ks], wfr[ks], acc[0][nt], 0, 0, 0);
            acc[1][nt] = __builtin_amdgcn_mfma_f32_16x16x32_bf16(af[1][ks], wfr[ks], acc[1][nt], 0, 0, 0);
        }
    }

    __syncthreads();
    ushort_t* So = &Sa[0][0];
#pragma unroll
    for (int nt = 0; nt < 2; ++nt) {
        int col = wn * 32 + nt * 16 + l;
        int gcol = n0 + col;
        float bv = bias[gcol];
        float qs = ((gcol % 96) < 32) ? QSCALE : 1.0f;
#pragma unroll
        for (int mt = 0; mt < 2; ++mt)
#pragma unroll
            for (int r = 0; r < 4; ++r) {
                int row = wm * 32 + mt * 16 + quad * 4 + r;
                So[row * 72 + col] = f2b((acc[mt][nt][r] + bv) * qs);
            }
    }
    __syncthreads();
    {
        int row = tid >> 2, seg = tid & 3;
        uint4 v0 = *(uint4*)&So[row * 72 + seg * 16];
        uint4 v1 = *(uint4*)&So[row * 72 + seg * 16 + 8];
        ushort_t* op = outb + (size_t)(m0 + row) * 768 + n0 + seg * 16;
        ((uint4*)op)[0] = v0;
        ((uint4*)op)[1] = v1;
    }

    int vs = n0 % 96;
    if (vs != 0) {
        int vloc = (vs == 64) ? 0 : 32;
        int h  = (n0 + vloc) / 96;
        int b  = m0 >> 11;
        int s0 = m0 & (S_ - 1);
        ushort_t* vstage = &Sa[0][0] + 8192;
        {
            int c = tid & 31, seg = tid >> 5;
            ushort_t tmp[8];
#pragma unroll
            for (int i = 0; i < 8; ++i)
                tmp[i] = So[(seg * 8 + i) * 72 + vloc + c];
            uint_t u[4];
#pragma unroll
            for (int i = 0; i < 4; ++i)
                u[i] = (uint_t)tmp[2 * i] | ((uint_t)tmp[2 * i + 1] << 16);
            *(uint4*)&vstage[c * 72 + seg * 8] = make_uint4(u[0], u[1], u[2], u[3]);
        }
        __syncthreads();
        {
            int d = tid >> 3, tseg = tid & 7;
            uint4 v = *(uint4*)&vstage[d * 72 + tseg * 8];
            *(uint4*)&vT[((size_t)(b * 8 + h) * 32 + d) * S_ + s0 + tseg * 8] = v;
        }
    }
}

// ---------------- fully fused post-attention (frag-ordered weights) ----------------
__global__ __launch_bounds__(256)
void fused_gate(const ushort_t* __restrict__ attn_b, const float* __restrict__ xf,
                const ushort_t* __restrict__ wfc, const ushort_t* __restrict__ wz,
                const ushort_t* __restrict__ uz, const ushort_t* __restrict__ wr,
                const ushort_t* __restrict__ ur, const ushort_t* __restrict__ wg,
                const ushort_t* __restrict__ ug, const float* __restrict__ bfc,
                const float* __restrict__ bz, float* __restrict__ out) {
    __shared__ ushort_t Sa[16][264];
    __shared__ ushort_t Sx[16][264];
    __shared__ ushort_t Sy[16][264];
    __shared__ ushort_t St[16][264];
    int tid = threadIdx.x;
    int wave = tid >> 6, lane = tid & 63, l = lane & 15, quad = lane >> 4;
    int m0 = blockIdx.x * 16;
    int colbase = wave * 64;

    {
        int row = tid >> 4, c0 = (tid & 15) * 16;
        const ushort_t* ap = attn_b + (size_t)(m0 + row) * 256 + c0;
        uint4 a0 = ((const uint4*)ap)[0];
        uint4 a1 = ((const uint4*)ap)[1];
        *(uint4*)&Sa[row][c0] = a0;
        *(uint4*)&Sa[row][c0 + 8] = a1;
        const float4* xp = (const float4*)(xf + (size_t)(m0 + row) * 256 + c0);
        float4 f0 = xp[0], f1 = xp[1], f2_ = xp[2], f3 = xp[3];
        union { __hip_bfloat162 h[4]; uint4 u; } p0, p1;
        p0.h[0] = __float22bfloat162_rn(make_float2(f0.x, f0.y));
        p0.h[1] = __float22bfloat162_rn(make_float2(f0.z, f0.w));
        p0.h[2] = __float22bfloat162_rn(make_float2(f1.x, f1.y));
        p0.h[3] = __float22bfloat162_rn(make_float2(f1.z, f1.w));
        p1.h[0] = __float22bfloat162_rn(make_float2(f2_.x, f2_.y));
        p1.h[1] = __float22bfloat162_rn(make_float2(f2_.z, f2_.w));
        p1.h[2] = __float22bfloat162_rn(make_float2(f3.x, f3.y));
        p1.h[3] = __float22bfloat162_rn(make_float2(f3.z, f3.w));
        *(uint4*)&Sx[row][c0]     = p0.u;
        *(uint4*)&Sx[row][c0 + 8] = p1.u;
    }
    __syncthreads();

    {
        bf16x8 af[8];
#pragma unroll
        for (int ks = 0; ks < 8; ++ks)
            af[ks] = *(const bf16x8*)&Sa[l][ks * 32 + quad * 8];
        f32x4 ya[4];
#pragma unroll
        for (int nt = 0; nt < 4; ++nt) ya[nt] = (f32x4){0.f, 0.f, 0.f, 0.f};
#pragma unroll
        for (int nt = 0; nt < 4; ++nt) {
            size_t fb = ((size_t)(wave * 4 + nt) * 8) * 512 + lane * 8;
#pragma unroll
            for (int ks = 0; ks < 8; ++ks) {
                bf16x8 wfr = *(const bf16x8*)(wfc + fb + ks * 512);
                ya[nt] = __builtin_amdgcn_mfma_f32_16x16x32_bf16(af[ks], wfr, ya[nt], 0, 0, 0);
            }
        }
#pragma unroll
        for (int nt = 0; nt < 4; ++nt) {
            int col = colbase + nt * 16 + l;
            float bv = bfc[col];
#pragma unroll
            for (int r = 0; r < 4; ++r)
                Sy[quad * 4 + r][col] = f2b(fmaxf(ya[nt][r] + bv, 0.0f));
        }
    }
    __syncthreads();

    f32x4 az[4], ar[4], ag[4];
#pragma unroll
    for (int nt = 0; nt < 4; ++nt) {
        az[nt] = (f32x4){0.f, 0.f, 0.f, 0.f};
        ar[nt] = (f32x4){0.f, 0.f, 0.f, 0.f};
        ag[nt] = (f32x4){0.f, 0.f, 0.f, 0.f};
    }
#pragma unroll
    for (int nt = 0; nt < 4; ++nt) {
        size_t fb = ((size_t)(wave * 4 + nt) * 8) * 512 + lane * 8;
#pragma unroll
        for (int ks = 0; ks < 8; ++ks) {
            bf16x8 fy = *(const bf16x8*)&Sy[l][ks * 32 + quad * 8];
            bf16x8 fx = *(const bf16x8*)&Sx[l][ks * 32 + quad * 8];
            bf16x8 fz  = *(const bf16x8*)(wz + fb + ks * 512);
            bf16x8 fuz = *(const bf16x8*)(uz + fb + ks * 512);
            bf16x8 fr  = *(const bf16x8*)(wr + fb + ks * 512);
            bf16x8 fur = *(const bf16x8*)(ur + fb + ks * 512);
            bf16x8 fg  = *(const bf16x8*)(wg + fb + ks * 512);
            az[nt] = __builtin_amdgcn_mfma_f32_16x16x32_bf16(fy, fz,  az[nt], 0, 0, 0);
            az[nt] = __builtin_amdgcn_mfma_f32_16x16x32_bf16(fx, fuz, az[nt], 0, 0, 0);
            ar[nt] = __builtin_amdgcn_mfma_f32_16x16x32_bf16(fy, fr,  ar[nt], 0, 0, 0);
            ar[nt] = __builtin_amdgcn_mfma_f32_16x16x32_bf16(fx, fur, ar[nt], 0, 0, 0);
            ag[nt] = __builtin_amdgcn_mfma_f32_16x16x32_bf16(fy, fg,  ag[nt], 0, 0, 0);
        }
    }
#pragma unroll
    for (int nt = 0; nt < 4; ++nt) {
        int col = colbase + nt * 16 + l;
        float bzv = bz[col];
#pragma unroll
        for (int r = 0; r < 4; ++r) {
            int row = quad * 4 + r;
            az[nt][r] = 1.0f / (1.0f + __expf(-(az[nt][r] + bzv)));
            float rr  = 1.0f / (1.0f + __expf(-ar[nt][r]));
            St[row][col] = f2b(rr * b2f(Sx[row][col]));
        }
    }
    __syncthreads();

    f32x4 fcc[4];
#pragma unroll
    for (int nt = 0; nt < 4; ++nt) fcc[nt] = (f32x4){0.f, 0.f, 0.f, 0.f};
#pragma unroll
    for (int nt = 0; nt < 4; ++nt) {
        size_t fb = ((size_t)(wave * 4 + nt) * 8) * 512 + lane * 8;
#pragma unroll
        for (int ks = 0; ks < 8; ++ks) {
            bf16x8 ft = *(const bf16x8*)&St[l][ks * 32 + quad * 8];
            bf16x8 fu = *(const bf16x8*)(ug + fb + ks * 512);
            fcc[nt] = __builtin_amdgcn_mfma_f32_16x16x32_bf16(ft, fu, fcc[nt], 0, 0, 0);
        }
    }
#pragma unroll
    for (int nt = 0; nt < 4; ++nt) {
        int col = colbase + nt * 16 + l;
#pragma unroll
        for (int r = 0; r < 4; ++r) {
            int row = quad * 4 + r;
            float v = ag[nt][r] + fcc[nt][r];
            float e = __expf(2.0f * v);
            float h = 1.0f - 2.0f / (e + 1.0f);
            float zz = az[nt][r];
            size_t idx = (size_t)(m0 + row) * 256 + col;
            out[idx] = (1.0f - zz) * xf[idx] + zz * h;
        }
    }
}

// ---------------- MFMA flash attention: LUT mask, ones-MFMA lsum, exp2 ----------------
// grid (S/64, B*H), block 256. Q pre-scaled by 1/sqrt(32)*log2e in QKV epilogue.
__global__ __launch_bounds__(256)
void attn_kernel(const ushort_t* __restrict__ qkvb, const ushort_t* __restrict__ vT,
                 const uint_t* __restrict__ abits, ushort_t* __restrict__ attn_b) {
    __shared__ ushort_t Ks[64][40];
    __shared__ ushort_t Vt[32][72];
    __shared__ ushort_t Ps[64][72];
    __shared__ uint2   lut[16];

    int tid = threadIdx.x;
    int wave = tid >> 6, lane = tid & 63, l = lane & 15, quad = lane >> 4;
    int q0 = blockIdx.x * 64;
    int n  = blockIdx.y;
    int b = n >> 3, h = n & 7;
    int bp = n & 3, hp = n >> 2;

    if (tid < 16)
        lut[tid] = make_uint2(((tid & 1) ? 0xFFFFu : 0u) | ((tid & 2) ? 0xFFFF0000u : 0u),
                              ((tid & 4) ? 0xFFFFu : 0u) | ((tid & 8) ? 0xFFFF0000u : 0u));

    const ushort_t* base = qkvb + (size_t)b * S_ * 768 + h * 96;
    int myq = wave * 16 + l;
    int qsh = quad * 4;

    bf16x8 qf = *(const bf16x8*)(base + (size_t)(q0 + myq) * 768 + quad * 8);

    bf16x8 ones;
#pragma unroll
    for (int i = 0; i < 8; ++i) ones[i] = (short)0x3F80;

    f32x4 oacc[2], aones;
    oacc[0] = (f32x4){0.f, 0.f, 0.f, 0.f};
    oacc[1] = (f32x4){0.f, 0.f, 0.f, 0.f};
    aones   = (f32x4){0.f, 0.f, 0.f, 0.f};

    int skey = tid >> 2, spart = tid & 3;
    int kcol = (spart * 8) ^ (((skey >> 3) & 1) << 3);
    int vd = tid >> 3, vk = (tid & 7) * 8;
    const ushort_t* vptr = vT + ((size_t)n * 32 + vd) * S_ + vk;
    const uint_t* aptr = abits + ((size_t)b * S_ + q0 + myq) * 64;

    uint4 kv = *(const uint4*)(base + (size_t)skey * 768 + 32 + spart * 8);
    uint4 vv = *(const uint4*)(vptr);
    uint2 aw = *(const uint2*)(aptr);

    for (int k0 = 0; k0 < S_; k0 += 64) {
        __syncthreads();   // previous iteration's LDS reads complete
        *(uint4*)&Ks[skey][kcol] = kv;
        *(uint4*)&Vt[vd][vk] = vv;
        uint_t aw0 = aw.x, aw1 = aw.y;
        if (k0 + 64 < S_) {
            kv = *(const uint4*)(base + (size_t)(k0 + 64 + skey) * 768 + 32 + spart * 8);
            vv = *(const uint4*)(vptr + k0 + 64);
            aw = *(const uint2*)(aptr + ((k0 + 64) >> 5));
        }
        __syncthreads();

#pragma unroll
        for (int t4 = 0; t4 < 4; ++t4) {
            bf16x8 kf = *(const bf16x8*)&Ks[t4 * 16 + l][(quad * 8) ^ ((l >> 3) << 3)];
            f32x4 z = (f32x4){0.f, 0.f, 0.f, 0.f};
            f32x4 sc = __builtin_amdgcn_mfma_f32_16x16x32_bf16(kf, qf, z, 0, 0, 0);
            uint_t w = (t4 & 2) ? aw1 : aw0;
            uint_t idx = (w >> ((t4 & 1) * 16 + qsh)) & 15u;
            uint2 mk = lut[idx];
            union { __hip_bfloat162 b2[2]; uint2 u2; } pk;
            pk.b2[0] = __float22bfloat162_rn(make_float2(exp2f(sc[0]), exp2f(sc[1])));
            pk.b2[1] = __float22bfloat162_rn(make_float2(exp2f(sc[2]), exp2f(sc[3])));
            pk.u2.x &= mk.x;
            pk.u2.y &= mk.y;
            *(uint2*)&Ps[myq][t4 * 16 + qsh] = pk.u2;
        }

#pragma unroll
        for (int ks = 0; ks < 2; ++ks) {
            bf16x8 pf = *(const bf16x8*)&Ps[wave * 16 + l][ks * 32 + quad * 8];
            aones = __builtin_amdgcn_mfma_f32_16x16x32_bf16(ones, pf, aones, 0, 0, 0);
#pragma unroll
            for (int mt = 0; mt < 2; ++mt) {
                bf16x8 vf = *(const bf16x8*)&Vt[mt * 16 + l][ks * 32 + quad * 8];
                oacc[mt] = __builtin_amdgcn_mfma_f32_16x16x32_bf16(vf, pf, oacc[mt], 0, 0, 0);
            }
        }
    }

    // every lane holds its own query's sum (D col = l), identical in all regs
    float linv = 1.0f / aones[0];

    __syncthreads();
    ushort_t* Ost = &Ks[0][0];   // stride 40
#pragma unroll
    for (int mt = 0; mt < 2; ++mt)
#pragma unroll
        for (int r = 0; r < 4; ++r)
            Ost[myq * 40 + mt * 16 + quad * 4 + r] = f2b(oacc[mt][r] * linv);
    __syncthreads();
    {
        int q = tid >> 2, part = tid & 3;
        uint4 v = *(uint4*)&Ost[q * 40 + part * 8];
        *(uint4*)&attn_b[((size_t)(bp * S_ + q0 + q)) * 256 + hp * 32 + part * 8] = v;
    }
}

// ---------------- launch ----------------
extern "C" void kernel_launch(void* const* d_in, const int* in_sizes, int n_in,
                              void* d_out, int out_size, void* d_ws, size_t ws_size,
                              hipStream_t stream) {
    const float* x     = (const float*)d_in[0];
    const int*   adj   = (const int*)d_in[1];
    const float* w_qkv = (const float*)d_in[2];
    const float* b_qkv = (const float*)d_in[3];
    const float* ln_g  = (const float*)d_in[4];
    const float* ln_b  = (const float*)d_in[5];
    const float* w_fc  = (const float*)d_in[6];
    const float* b_fc  = (const float*)d_in[7];
    const float* w_z   = (const float*)d_in[8];
    const float* b_z   = (const float*)d_in[9];
    const float* u_z   = (const float*)d_in[10];
    const float* w_r   = (const float*)d_in[11];
    const float* u_r   = (const float*)d_in[12];
    const float* w_g   = (const float*)d_in[13];
    const float* u_g   = (const float*)d_in[14];
    float* out = (float*)d_out;

    const size_t TOK  = (size_t)B_ * S_;       // 8192
    const size_t TOKD = TOK * D_;              // 2,097,152
    ushort_t* xn_b   = (ushort_t*)d_ws;
    ushort_t* qkv_b  = xn_b + TOKD;            // TOK*768
    ushort_t* attn_b = qkv_b + TOK * 768;
    ushort_t* wb     = attn_b + TOKD;          // 655,360 elems (frag-ordered)
    uint_t*   bits   = (uint_t*)(wb + WQ_SZ + 7 * WS_SZ);   // 524,288 words
    ushort_t* vTb    = (ushort_t*)(bits + (size_t)B_ * S_ * S_ / 32);  // 1024*2048

    ushort_t* wq_b  = wb;
    ushort_t* wfc_b = wb + WQ_SZ;
    ushort_t* wz_b  = wfc_b + WS_SZ;
    ushort_t* uz_b  = wz_b + WS_SZ;
    ushort_t* wr_b  = uz_b + WS_SZ;
    ushort_t* ur_b  = wr_b + WS_SZ;
    ushort_t* wg_b  = ur_b + WS_SZ;
    ushort_t* ug_b  = wg_b + WS_SZ;

    prep_kernel<<<NB_ADJ + NB_WC + NB_LN, 256, 0, stream>>>(
        adj, bits, w_qkv, w_fc, w_z, u_z, w_r, u_r, w_g, u_g, wb,
        x, ln_g, ln_b, xn_b);

    gemm_qkv<<<dim3(12, 128), 256, 0, stream>>>(xn_b, wq_b, b_qkv, qkv_b, vTb);

    attn_kernel<<<dim3(S_ / 64, B_ * H_), 256, 0, stream>>>(qkv_b, vTb, bits, attn_b);

    fused_gate<<<512, 256, 0, stream>>>(
        attn_b, x, wfc_b, wz_b, uz_b, wr_b, ur_b, wg_b, ug_b, b_fc, b_z, out);
}